// Round 1
// baseline (60.610 us; speedup 1.0000x reference)
//
#include <hip/hip_runtime.h>
#include <hip/hip_bf16.h>
#include <math.h>

// Problem constants
#define Bn    8
#define Sn    8
#define CINc  64
#define Hh    32
#define Wwi   32
#define COUTc 128
#define PWc   73728
#define Pc    73856
#define WOc   30
#define NPIX  900      // 30*30 per (b,s)
#define GPIX  7200     // B*NPIX per s
#define KTOT  576      // CIN*3*3
#define BKc   32
#define PIXT  64
#define NTILES 113     // ceil(7200/64)
#define LDP   (BKc + 8) // padded LDS row stride (80 B, 16B-aligned)

typedef __bf16 bf16;
typedef bf16  bf16x8 __attribute__((ext_vector_type(8)));
typedef float f32x4  __attribute__((ext_vector_type(4)));

static_assert(sizeof(bf16) == 2, "bf16 size");

__device__ __forceinline__ float softplus_f(float x) {
    return fmaxf(x, 0.f) + log1pf(expf(-fabsf(x)));
}

// ---------------------------------------------------------------------------
// Kernel A: sample weights/biases (store w as bf16 [S][PW], b as f32 [S][COUT])
// and accumulate KL partials: partials[0] = sum(log sig), partials[1] = sum sq.
// ---------------------------------------------------------------------------
__global__ __launch_bounds__(256) void prep_kernel(
        const float* __restrict__ e,
        const float* __restrict__ mu_w, const float* __restrict__ rho_w,
        const float* __restrict__ mu_b, const float* __restrict__ rho_b,
        bf16* __restrict__ wq, float* __restrict__ bq,
        float* __restrict__ partials) {
    int i = blockIdx.x * blockDim.x + threadIdx.x;
    float ls = 0.f, sq = 0.f;
    if (i < PWc) {
        float sig = softplus_f(rho_w[i]);
        ls = logf(sig);
        float mu = mu_w[i];
        #pragma unroll
        for (int s = 0; s < Sn; ++s) {
            float wv = fmaf(sig, e[s * Pc + i], mu);
            wq[s * PWc + i] = (bf16)wv;
            sq += wv * wv;
        }
    } else if (i < Pc) {
        int c = i - PWc;
        float sig = softplus_f(rho_b[c]);
        ls = logf(sig);
        float mu = mu_b[c];
        #pragma unroll
        for (int s = 0; s < Sn; ++s) {
            float bv = fmaf(sig, e[s * Pc + i], mu);
            bq[s * COUTc + c] = bv;
            sq += bv * bv;
        }
    }
    // wave reduce (64 lanes), then cross-wave via LDS, then one atomic per block
    #pragma unroll
    for (int off = 32; off > 0; off >>= 1) {
        ls += __shfl_down(ls, off);
        sq += __shfl_down(sq, off);
    }
    __shared__ float sls[4], ssq[4];
    int lane = threadIdx.x & 63, wid = threadIdx.x >> 6;
    if (lane == 0) { sls[wid] = ls; ssq[wid] = sq; }
    __syncthreads();
    if (threadIdx.x == 0) {
        atomicAdd(&partials[0], sls[0] + sls[1] + sls[2] + sls[3]);
        atomicAdd(&partials[1], ssq[0] + ssq[1] + ssq[2] + ssq[3]);
    }
}

__global__ void finalize_kl(const float* __restrict__ partials,
                            float* __restrict__ out_kl) {
    // kl = -sum(log sig) + log(2pi)*(PW+COUT)/2 + 0.5*sum_sq
    float kl = -partials[0] + 0.91893853320467274f * (float)(PWc + COUTc)
             + 0.5f * partials[1];
    *out_kl = kl;
}

// ---------------------------------------------------------------------------
// Kernel C: implicit-GEMM conv via MFMA bf16.
// Per block: one s, tile of 64 global pixels (g = b*900 + y*30 + x), all 128 co.
// 4 waves in 2x2: wave tile = 64co x 32pix, 8 MFMA (16x16x32) per K-step.
// ---------------------------------------------------------------------------
__global__ __launch_bounds__(256) void conv_mfma(
        const float* __restrict__ xg, const bf16* __restrict__ wq,
        const float* __restrict__ bq, float* __restrict__ out) {
    const int s    = blockIdx.y;
    const int tile = blockIdx.x;
    const int t    = threadIdx.x;
    const int lane = t & 63;
    const int wid  = t >> 6;
    const int wr   = wid >> 1;   // co half (0/1)
    const int wc   = wid & 1;    // pix half (0/1)

    __shared__ bf16 Alds[COUTc][LDP];   // W tile [128][32] (+pad)
    __shared__ bf16 Xlds[PIXT][LDP];    // X^T tile [64 pix][32 k] (+pad)
    __shared__ unsigned short lut[KTOT]; // k -> ci*1024 + ky*32 + kx (<=64578)

    for (int k = t; k < KTOT; k += 256) {
        int ci = k / 9, rr = k - ci * 9;
        int ky = rr / 3, kx = rr - ky * 3;
        lut[k] = (unsigned short)(ci * 1024 + ky * 32 + kx);
    }

    // per-thread staging pixel (fixed across K loop)
    const int  pixl  = t & 63;
    const int  koct  = t >> 6;           // which 8-k group this thread stages
    const int  g     = tile * PIXT + pixl;
    const bool valid = (g < GPIX);
    const int  gs    = valid ? g : 0;
    const int  bb    = gs / NPIX;
    const int  r     = gs - bb * NPIX;
    const int  oy    = r / WOc;
    const int  ox    = r - oy * WOc;
    const float* xbase = xg + ((bb * Sn + s) << 16) + oy * Wwi + ox;

    const bf16* wbase = wq + s * PWc;
    const int arow0 = t >> 2;            // 0..63 (and +64 for 2nd chunk)
    const int aq    = (t & 3) * 8;       // k sub-offset (elements)

    f32x4 acc[4][2];
    #pragma unroll
    for (int i = 0; i < 4; ++i)
        #pragma unroll
        for (int j = 0; j < 2; ++j)
            acc[i][j] = f32x4{0.f, 0.f, 0.f, 0.f};

    __syncthreads(); // lut ready

    for (int step = 0; step < KTOT / BKc; ++step) {
        const int k0 = step * BKc;

        // --- issue global loads into regs before the barrier (latency overlap)
        uint4 a0 = *reinterpret_cast<const uint4*>(wbase + arow0 * KTOT + k0 + aq);
        uint4 a1 = *reinterpret_cast<const uint4*>(wbase + (arow0 + 64) * KTOT + k0 + aq);

        unsigned int xp[4];
        #pragma unroll
        for (int jj = 0; jj < 4; ++jj) {
            float v0 = 0.f, v1 = 0.f;
            if (valid) {
                int k = k0 + koct * 8 + 2 * jj;
                v0 = xbase[lut[k]];
                v1 = xbase[lut[k + 1]];
            }
            unsigned short u0 = __builtin_bit_cast(unsigned short, (bf16)v0);
            unsigned short u1 = __builtin_bit_cast(unsigned short, (bf16)v1);
            xp[jj] = ((unsigned int)u1 << 16) | (unsigned int)u0;
        }

        __syncthreads(); // previous iteration's frag reads complete
        *reinterpret_cast<uint4*>(&Alds[arow0][aq])      = a0;
        *reinterpret_cast<uint4*>(&Alds[arow0 + 64][aq]) = a1;
        uint4 xw; xw.x = xp[0]; xw.y = xp[1]; xw.z = xp[2]; xw.w = xp[3];
        *reinterpret_cast<uint4*>(&Xlds[pixl][koct * 8]) = xw;
        __syncthreads(); // tiles ready

        // fragments: A lane l holds A[row=l&15][k=(l>>4)*8+j]; B lane l holds
        // B[k=(l>>4)*8+j][col=l&15] -> X^T row = pix, cols = contiguous k.
        bf16x8 afr[4], bfr[2];
        #pragma unroll
        for (int fm = 0; fm < 4; ++fm)
            afr[fm] = *reinterpret_cast<const bf16x8*>(
                &Alds[wr * 64 + fm * 16 + (lane & 15)][(lane >> 4) * 8]);
        #pragma unroll
        for (int fn = 0; fn < 2; ++fn)
            bfr[fn] = *reinterpret_cast<const bf16x8*>(
                &Xlds[wc * 32 + fn * 16 + (lane & 15)][(lane >> 4) * 8]);

        #pragma unroll
        for (int fm = 0; fm < 4; ++fm)
            #pragma unroll
            for (int fn = 0; fn < 2; ++fn)
                acc[fm][fn] = __builtin_amdgcn_mfma_f32_16x16x32_bf16(
                    afr[fm], bfr[fn], acc[fm][fn], 0, 0, 0);
    }

    // epilogue: D mapping col(pix)=lane&15, row(co)=(lane>>4)*4+reg
    float bias[4][4];
    #pragma unroll
    for (int fm = 0; fm < 4; ++fm)
        #pragma unroll
        for (int j = 0; j < 4; ++j)
            bias[fm][j] = bq[s * COUTc + wr * 64 + fm * 16 + (lane >> 4) * 4 + j];

    #pragma unroll
    for (int fn = 0; fn < 2; ++fn) {
        int pl = wc * 32 + fn * 16 + (lane & 15);
        int gg = tile * PIXT + pl;
        if (gg >= GPIX) continue;
        int b2 = gg / NPIX;
        int r2 = gg - b2 * NPIX;
        float* obase = out + (b2 * Sn + s) * (COUTc * NPIX) + r2;
        #pragma unroll
        for (int fm = 0; fm < 4; ++fm) {
            int cobase = wr * 64 + fm * 16 + (lane >> 4) * 4;
            #pragma unroll
            for (int j = 0; j < 4; ++j)
                obase[(cobase + j) * NPIX] = acc[fm][fn][j] + bias[fm][j];
        }
    }
}

// ---------------------------------------------------------------------------
extern "C" void kernel_launch(void* const* d_in, const int* in_sizes, int n_in,
                              void* d_out, int out_size, void* d_ws, size_t ws_size,
                              hipStream_t stream) {
    const float* x     = (const float*)d_in[0];
    const float* e     = (const float*)d_in[1];
    const float* mu_w  = (const float*)d_in[2];
    const float* rho_w = (const float*)d_in[3];
    const float* mu_b  = (const float*)d_in[4];
    const float* rho_b = (const float*)d_in[5];
    float* out = (float*)d_out;

    // workspace layout
    bf16*  wq       = (bf16*)d_ws;                          // 1,179,648 B
    float* bq       = (float*)((char*)d_ws + 1179648);      // 4,096 B
    float* partials = (float*)((char*)d_ws + 1183744);      // 8 B

    hipMemsetAsync(partials, 0, 2 * sizeof(float), stream);

    prep_kernel<<<dim3((Pc + 255) / 256), dim3(256), 0, stream>>>(
        e, mu_w, rho_w, mu_b, rho_b, wq, bq, partials);

    conv_mfma<<<dim3(NTILES, Sn), dim3(256), 0, stream>>>(x, wq, bq, out);

    finalize_kl<<<1, 1, 0, stream>>>(partials, out + (out_size - 1));
}